// Round 4
// baseline (764.467 us; speedup 1.0000x reference)
//
#include <hip/hip_runtime.h>

#define BSHIFT 7
#define BSIZE 128          // nodes per bucket
#define MAXB 1024          // max buckets (N <= 131072); col must fit 17 bits
#define CHUNK 16384        // edges per block in bucket passes

typedef unsigned short bfraw;

__device__ __forceinline__ bfraw f2bf(float f) {
    unsigned u = __float_as_uint(f);
    unsigned r = u + 0x7FFFu + ((u >> 16) & 1u);   // round-to-nearest-even
    return (bfraw)(r >> 16);
}
__device__ __forceinline__ float bf2f(bfraw h) {
    return __uint_as_float(((unsigned)h) << 16);
}

// ---------------- bucketed CSR build ----------------

__global__ __launch_bounds__(256) void k_bhist(const int* __restrict__ row,
                                               int* __restrict__ bhist,
                                               int E, int nbuckets) {
    __shared__ int h[MAXB];
    for (int i = threadIdx.x; i < nbuckets; i += 256) h[i] = 0;
    __syncthreads();
    int start = blockIdx.x * CHUNK;
    int end = min(E, start + CHUNK);
    for (int i = start + threadIdx.x; i < end; i += 256)
        atomicAdd(&h[row[i] >> BSHIFT], 1);
    __syncthreads();
    for (int i = threadIdx.x; i < nbuckets; i += 256)
        if (h[i]) atomicAdd(&bhist[i], h[i]);
}

__global__ __launch_bounds__(1024) void k_bscan(const int* __restrict__ bhist,
                                                int* __restrict__ boff,
                                                int* __restrict__ bcur,
                                                int nbuckets, int E) {
    __shared__ int sd[1024];
    int t = threadIdx.x;
    int v = (t < nbuckets) ? bhist[t] : 0;
    sd[t] = v;
    __syncthreads();
    for (int d = 1; d < 1024; d <<= 1) {
        int a = (t >= d) ? sd[t - d] : 0;
        __syncthreads();
        sd[t] += a;
        __syncthreads();
    }
    if (t < nbuckets) { int ex = sd[t] - v; boff[t] = ex; bcur[t] = ex; }
    if (t == 0) boff[nbuckets] = E;
}

// scatter edges grouped by bucket; pack (localrow<<17 | col) into one int
__global__ __launch_bounds__(256) void k_bscatter(const int* __restrict__ row,
                                                  const int* __restrict__ col,
                                                  int* __restrict__ bcur,
                                                  int* __restrict__ bedge,
                                                  int E, int nbuckets) {
    __shared__ int h[MAXB];
    __shared__ int base[MAXB];
    for (int i = threadIdx.x; i < nbuckets; i += 256) h[i] = 0;
    __syncthreads();
    int start = blockIdx.x * CHUNK;
    int end = min(E, start + CHUNK);
    for (int i = start + threadIdx.x; i < end; i += 256)
        atomicAdd(&h[row[i] >> BSHIFT], 1);
    __syncthreads();
    for (int i = threadIdx.x; i < nbuckets; i += 256) {
        int c = h[i];
        base[i] = c ? atomicAdd(&bcur[i], c) : 0;
        h[i] = 0;
    }
    __syncthreads();
    for (int i = start + threadIdx.x; i < end; i += 256) {
        int r = row[i], c = col[i];
        int b = r >> BSHIFT;
        int p = base[b] + atomicAdd(&h[b], 1);
        bedge[p] = ((r & (BSIZE - 1)) << 17) | c;
    }
}

// block per bucket: bucket-grouped edges -> exact CSR (scol, off) + invs.
__global__ __launch_bounds__(256) void k_bexact(const int* __restrict__ bedge,
                                                const int* __restrict__ boff,
                                                int* __restrict__ off,
                                                int* __restrict__ scol,
                                                float* __restrict__ invs,
                                                int N, int E) {
    __shared__ int ldeg[BSIZE];
    __shared__ int lex[BSIZE];
    int b = blockIdx.x;
    int tid = threadIdx.x;
    int nstart = b << BSHIFT;
    int ncount = min(BSIZE, N - nstart);
    int s = boff[b], e = boff[b + 1];
    if (tid < BSIZE) ldeg[tid] = 0;
    __syncthreads();
    for (int k = s + tid; k < e; k += 256)
        atomicAdd(&ldeg[bedge[k] >> 17], 1);
    __syncthreads();
    if (tid < BSIZE) lex[tid] = ldeg[tid];
    __syncthreads();
    for (int d = 1; d < BSIZE; d <<= 1) {
        int a = 0;
        if (tid < BSIZE && tid >= d) a = lex[tid - d];
        __syncthreads();
        if (tid < BSIZE) lex[tid] += a;
        __syncthreads();
    }
    if (tid < BSIZE) lex[tid] -= ldeg[tid];   // exclusive scan
    __syncthreads();
    if (tid < ncount) {
        int node = nstart + tid;
        off[node] = s + lex[tid];
        invs[node] = rsqrtf((float)(ldeg[tid] + 1));
    }
    if (b == 0 && tid == 0) off[N] = E;
    if (tid < BSIZE) ldeg[tid] = 0;           // reuse as per-node cursor
    __syncthreads();
    for (int k = s + tid; k < e; k += 256) {
        int p = bedge[k];
        int lr = p >> 17;
        int pos = s + lex[lr] + atomicAdd(&ldeg[lr], 1);
        scol[pos] = p & 0x1FFFF;
    }
}

// ---------------- projections (store invs[row]-scaled, bf16) ----------------

__global__ __launch_bounds__(256) void k_gemm0(const float* __restrict__ x,
                                               const float* __restrict__ W,
                                               const float* __restrict__ invs,
                                               bfraw* __restrict__ out, int N) {
    __shared__ float sW[128 * 64];
    for (int i = threadIdx.x; i < 128 * 64; i += 256) sW[i] = W[i];
    __syncthreads();
    int row = blockIdx.x * 4 + (threadIdx.x >> 6);
    int c = threadIdx.x & 63;
    if (row >= N) return;
    const float4* xr = (const float4*)(x + (size_t)row * 128);
    float acc = 0.f;
#pragma unroll
    for (int k4 = 0; k4 < 32; ++k4) {
        float4 xv = xr[k4];
        int k = k4 * 4;
        acc = fmaf(xv.x, sW[(k + 0) * 64 + c], acc);
        acc = fmaf(xv.y, sW[(k + 1) * 64 + c], acc);
        acc = fmaf(xv.z, sW[(k + 2) * 64 + c], acc);
        acc = fmaf(xv.w, sW[(k + 3) * 64 + c], acc);
    }
    out[(size_t)row * 64 + c] = f2bf(invs[row] * acc);
}

__global__ __launch_bounds__(256) void k_gemm1(const float* __restrict__ h,
                                               const float* __restrict__ W,
                                               const float* __restrict__ invs,
                                               bfraw* __restrict__ out, int N) {
    __shared__ float sW[64 * 32];
    for (int i = threadIdx.x; i < 64 * 32; i += 256) sW[i] = W[i];
    __syncthreads();
    int row = blockIdx.x * 8 + (threadIdx.x >> 5);
    int c = threadIdx.x & 31;
    if (row >= N) return;
    const float4* hr = (const float4*)(h + (size_t)row * 64);
    float acc = 0.f;
#pragma unroll
    for (int k4 = 0; k4 < 16; ++k4) {
        float4 hv = hr[k4];
        int k = k4 * 4;
        acc = fmaf(hv.x, sW[(k + 0) * 32 + c], acc);
        acc = fmaf(hv.y, sW[(k + 1) * 32 + c], acc);
        acc = fmaf(hv.z, sW[(k + 2) * 32 + c], acc);
        acc = fmaf(hv.w, sW[(k + 3) * 32 + c], acc);
    }
    out[(size_t)row * 32 + c] = f2bf(invs[row] * acc);
}

// ---------------- CSR gather-aggregate (bf16 tables, f32 accumulate) -------

__global__ __launch_bounds__(256) void k_csr_agg64(const int* __restrict__ scol,
                                                   const int* __restrict__ off,
                                                   const float* __restrict__ invs,
                                                   const bfraw* __restrict__ hWb,
                                                   const float* __restrict__ bias,
                                                   float* __restrict__ h0, int N) {
    int i = blockIdx.x;
    int lane = threadIdx.x & 63, w = threadIdx.x >> 6;
    int s = off[i], e = off[i + 1];
    float a0 = 0.f, a1 = 0.f;
    int k = s + w;
    for (; k + 4 < e; k += 8) {
        int c0 = scol[k], c1 = scol[k + 4];
        a0 += bf2f(hWb[(size_t)c0 * 64 + lane]);
        a1 += bf2f(hWb[(size_t)c1 * 64 + lane]);
    }
    if (k < e) a0 += bf2f(hWb[(size_t)scol[k] * 64 + lane]);
    __shared__ float red[4][64];
    red[w][lane] = a0 + a1;
    __syncthreads();
    if (threadIdx.x < 64) {
        float v = red[0][lane] + red[1][lane] + red[2][lane] + red[3][lane];
        v = invs[i] * (v + bf2f(hWb[(size_t)i * 64 + lane])) + bias[lane];
        h0[(size_t)i * 64 + lane] = v > 0.f ? v : 0.f;
    }
}

__global__ __launch_bounds__(256) void k_csr_agg32_pool(const int* __restrict__ scol,
                                                        const int* __restrict__ off,
                                                        const float* __restrict__ invs,
                                                        const bfraw* __restrict__ hWb,
                                                        const float* __restrict__ bias,
                                                        const int* __restrict__ gidx,
                                                        float* __restrict__ pooled,
                                                        int N) {
    int i = blockIdx.x;
    int lane = threadIdx.x & 31, w = threadIdx.x >> 5;
    int s = off[i], e = off[i + 1];
    float a0 = 0.f, a1 = 0.f;
    int k = s + w;
    for (; k + 8 < e; k += 16) {
        int c0 = scol[k], c1 = scol[k + 8];
        a0 += bf2f(hWb[(size_t)c0 * 32 + lane]);
        a1 += bf2f(hWb[(size_t)c1 * 32 + lane]);
    }
    if (k < e) a0 += bf2f(hWb[(size_t)scol[k] * 32 + lane]);
    __shared__ float red[8][32];
    red[w][lane] = a0 + a1;
    __syncthreads();
    if (threadIdx.x < 32) {
        float v = 0.f;
#pragma unroll
        for (int q = 0; q < 8; ++q) v += red[q][lane];
        v = invs[i] * (v + bf2f(hWb[(size_t)i * 32 + lane])) + bias[lane];
        v = v > 0.f ? v : 0.f;
        atomicAdd(&pooled[(size_t)gidx[i] * 32 + lane], v);
    }
}

__global__ __launch_bounds__(256) void k_cnt(const int* __restrict__ gidx,
                                             int* __restrict__ cnt, int N) {
    int i = blockIdx.x * 256 + threadIdx.x;
    if (i < N) atomicAdd(&cnt[gidx[i]], 1);
}

__global__ __launch_bounds__(256) void k_final(const float* __restrict__ pooled,
                                               const int* __restrict__ cnt,
                                               const float* __restrict__ Wd,
                                               const float* __restrict__ bd,
                                               float* __restrict__ out, int total) {
    int idx = blockIdx.x * 256 + threadIdx.x;
    if (idx >= total) return;
    int g = idx >> 4, c = idx & 15;
    float denom = fmaxf((float)cnt[g], 1.0f);
    float acc = 0.f;
#pragma unroll
    for (int j = 0; j < 32; ++j)
        acc = fmaf(pooled[g * 32 + j], Wd[j * 16 + c], acc);
    out[idx] = acc / denom + bd[c];
}

// ---------------- launch ----------------

extern "C" void kernel_launch(void* const* d_in, const int* in_sizes, int n_in,
                              void* d_out, int out_size, void* d_ws, size_t ws_size,
                              hipStream_t stream) {
    const float* x   = (const float*)d_in[0];
    const int*  erow = (const int*)d_in[1];              // edge targets
    const int*  gidx = (const int*)d_in[2];
    const float* W0  = (const float*)d_in[3];
    const float* b0  = (const float*)d_in[4];
    const float* W1  = (const float*)d_in[5];
    const float* b1  = (const float*)d_in[6];
    const float* Wd  = (const float*)d_in[7];
    const float* bd  = (const float*)d_in[8];
    float* out = (float*)d_out;

    const int E = in_sizes[1] / 2;
    const int* ecol = erow + E;                          // edge sources
    const int N = in_sizes[2];
    const int G = out_size / 16;
    const int nbuckets = (N + BSIZE - 1) / BSIZE;
    const int nchunks = (E + CHUNK - 1) / CHUNK;

    char* ws = (char*)d_ws;
    size_t oInvs = 0;                                    // N floats
    size_t oOff  = oInvs + (size_t)N * 4;                // (N+8) ints
    size_t oBh   = oOff + (size_t)(N + 8) * 4;           // MAXB ints
    size_t oBo   = oBh + (size_t)MAXB * 4;               // MAXB+8 ints
    size_t oBc   = oBo + (size_t)(MAXB + 8) * 4;         // MAXB ints
    size_t oScol = oBc + (size_t)MAXB * 4;               // E ints
    size_t oA    = oScol + (size_t)E * 4;                // N*64 bf16 table (layer0; reused N*32 layer1)
    size_t oB    = oA + (size_t)N * 128;                 // max(E*4, N*64*4): bedge early, h0 later
    size_t oP    = oB + (size_t)N * 256;                 // G*32 floats pooled
    size_t oCnt  = oP + (size_t)G * 128;                 // G ints

    float* invs   = (float*)(ws + oInvs);
    int*   off    = (int*)(ws + oOff);
    int*   bhist  = (int*)(ws + oBh);
    int*   boff   = (int*)(ws + oBo);
    int*   bcur   = (int*)(ws + oBc);
    int*   scol   = (int*)(ws + oScol);
    bfraw* tabA   = (bfraw*)(ws + oA);
    float* bufB   = (float*)(ws + oB);
    float* pooled = (float*)(ws + oP);
    int*   cnt    = (int*)(ws + oCnt);
    int*   bedge  = (int*)bufB;                          // dead before h0 is written

    hipMemsetAsync(bhist, 0, (size_t)MAXB * 4, stream);
    hipMemsetAsync(pooled, 0, (size_t)G * 128 + (size_t)G * 4, stream);

    // CSR build via two-level counting sort (also yields deg -> invs)
    k_bhist<<<nchunks, 256, 0, stream>>>(erow, bhist, E, nbuckets);
    k_bscan<<<1, 1024, 0, stream>>>(bhist, boff, bcur, nbuckets, E);
    k_bscatter<<<nchunks, 256, 0, stream>>>(erow, ecol, bcur, bedge, E, nbuckets);
    k_bexact<<<nbuckets, 256, 0, stream>>>(bedge, boff, off, scol, invs, N, E);

    // layer 0: project (invs-scaled, bf16) then gather-aggregate
    k_gemm0<<<(N + 3) / 4, 256, 0, stream>>>(x, W0, invs, tabA, N);
    k_csr_agg64<<<N, 256, 0, stream>>>(scol, off, invs, tabA, b0, bufB, N);

    // layer 1: project then gather-aggregate fused with mean-pool
    k_gemm1<<<(N + 7) / 8, 256, 0, stream>>>(bufB, W1, invs, tabA, N);
    k_csr_agg32_pool<<<N, 256, 0, stream>>>(scol, off, invs, tabA, b1, gidx, pooled, N);
    k_cnt<<<(N + 255) / 256, 256, 0, stream>>>(gidx, cnt, N);

    // dense head
    k_final<<<(G * 16 + 255) / 256, 256, 0, stream>>>(pooled, cnt, Wd, bd, out, G * 16);
}

// Round 5
// 593.492 us; speedup vs baseline: 1.2881x; 1.2881x over previous
//
#include <hip/hip_runtime.h>

#define BSHIFT 7
#define BSIZE 128          // nodes per bucket
#define MAXB 1024          // max buckets (N <= 131072); col must fit 17 bits
#define CHUNK 16384        // edges per block in bucket passes

typedef unsigned short bfraw;

__device__ __forceinline__ bfraw f2bf(float f) {
    unsigned u = __float_as_uint(f);
    unsigned r = u + 0x7FFFu + ((u >> 16) & 1u);   // round-to-nearest-even
    return (bfraw)(r >> 16);
}
__device__ __forceinline__ float bf2f(bfraw h) {
    return __uint_as_float(((unsigned)h) << 16);
}
__device__ __forceinline__ float bflo(unsigned u) { return __uint_as_float(u << 16); }
__device__ __forceinline__ float bfhi(unsigned u) { return __uint_as_float(u & 0xFFFF0000u); }

// ---------------- bucketed CSR build ----------------

__global__ __launch_bounds__(256) void k_bhist(const int* __restrict__ row,
                                               int* __restrict__ bhist,
                                               int E, int nbuckets) {
    __shared__ int h[MAXB];
    for (int i = threadIdx.x; i < nbuckets; i += 256) h[i] = 0;
    __syncthreads();
    int start = blockIdx.x * CHUNK;
    int end = min(E, start + CHUNK);
    for (int i = start + threadIdx.x; i < end; i += 256)
        atomicAdd(&h[row[i] >> BSHIFT], 1);
    __syncthreads();
    for (int i = threadIdx.x; i < nbuckets; i += 256)
        if (h[i]) atomicAdd(&bhist[i], h[i]);
}

__global__ __launch_bounds__(1024) void k_bscan(const int* __restrict__ bhist,
                                                int* __restrict__ boff,
                                                int* __restrict__ bcur,
                                                int nbuckets, int E) {
    __shared__ int sd[1024];
    int t = threadIdx.x;
    int v = (t < nbuckets) ? bhist[t] : 0;
    sd[t] = v;
    __syncthreads();
    for (int d = 1; d < 1024; d <<= 1) {
        int a = (t >= d) ? sd[t - d] : 0;
        __syncthreads();
        sd[t] += a;
        __syncthreads();
    }
    if (t < nbuckets) { int ex = sd[t] - v; boff[t] = ex; bcur[t] = ex; }
    if (t == 0) boff[nbuckets] = E;
}

__global__ __launch_bounds__(256) void k_bscatter(const int* __restrict__ row,
                                                  const int* __restrict__ col,
                                                  int* __restrict__ bcur,
                                                  int* __restrict__ bedge,
                                                  int E, int nbuckets) {
    __shared__ int h[MAXB];
    __shared__ int base[MAXB];
    for (int i = threadIdx.x; i < nbuckets; i += 256) h[i] = 0;
    __syncthreads();
    int start = blockIdx.x * CHUNK;
    int end = min(E, start + CHUNK);
    for (int i = start + threadIdx.x; i < end; i += 256)
        atomicAdd(&h[row[i] >> BSHIFT], 1);
    __syncthreads();
    for (int i = threadIdx.x; i < nbuckets; i += 256) {
        int c = h[i];
        base[i] = c ? atomicAdd(&bcur[i], c) : 0;
        h[i] = 0;
    }
    __syncthreads();
    for (int i = start + threadIdx.x; i < end; i += 256) {
        int r = row[i], c = col[i];
        int b = r >> BSHIFT;
        int p = base[b] + atomicAdd(&h[b], 1);
        bedge[p] = ((r & (BSIZE - 1)) << 17) | c;
    }
}

__global__ __launch_bounds__(256) void k_bexact(const int* __restrict__ bedge,
                                                const int* __restrict__ boff,
                                                int* __restrict__ off,
                                                int* __restrict__ scol,
                                                float* __restrict__ invs,
                                                int N, int E) {
    __shared__ int ldeg[BSIZE];
    __shared__ int lex[BSIZE];
    int b = blockIdx.x;
    int tid = threadIdx.x;
    int nstart = b << BSHIFT;
    int ncount = min(BSIZE, N - nstart);
    int s = boff[b], e = boff[b + 1];
    if (tid < BSIZE) ldeg[tid] = 0;
    __syncthreads();
    for (int k = s + tid; k < e; k += 256)
        atomicAdd(&ldeg[bedge[k] >> 17], 1);
    __syncthreads();
    if (tid < BSIZE) lex[tid] = ldeg[tid];
    __syncthreads();
    for (int d = 1; d < BSIZE; d <<= 1) {
        int a = 0;
        if (tid < BSIZE && tid >= d) a = lex[tid - d];
        __syncthreads();
        if (tid < BSIZE) lex[tid] += a;
        __syncthreads();
    }
    if (tid < BSIZE) lex[tid] -= ldeg[tid];   // exclusive scan
    __syncthreads();
    if (tid < ncount) {
        int node = nstart + tid;
        off[node] = s + lex[tid];
        invs[node] = rsqrtf((float)(ldeg[tid] + 1));
    }
    if (b == 0 && tid == 0) off[N] = E;
    if (tid < BSIZE) ldeg[tid] = 0;           // reuse as per-node cursor
    __syncthreads();
    for (int k = s + tid; k < e; k += 256) {
        int p = bedge[k];
        int lr = p >> 17;
        int pos = s + lex[lr] + atomicAdd(&ldeg[lr], 1);
        scol[pos] = p & 0x1FFFF;
    }
}

// ---------------- projections (store invs[row]-scaled, bf16) ----------------

__global__ __launch_bounds__(256) void k_gemm0(const float* __restrict__ x,
                                               const float* __restrict__ W,
                                               const float* __restrict__ invs,
                                               bfraw* __restrict__ out, int N) {
    __shared__ float sW[128 * 64];
    for (int i = threadIdx.x; i < 128 * 64; i += 256) sW[i] = W[i];
    __syncthreads();
    int row = blockIdx.x * 4 + (threadIdx.x >> 6);
    int c = threadIdx.x & 63;
    if (row >= N) return;
    const float4* xr = (const float4*)(x + (size_t)row * 128);
    float acc = 0.f;
#pragma unroll
    for (int k4 = 0; k4 < 32; ++k4) {
        float4 xv = xr[k4];
        int k = k4 * 4;
        acc = fmaf(xv.x, sW[(k + 0) * 64 + c], acc);
        acc = fmaf(xv.y, sW[(k + 1) * 64 + c], acc);
        acc = fmaf(xv.z, sW[(k + 2) * 64 + c], acc);
        acc = fmaf(xv.w, sW[(k + 3) * 64 + c], acc);
    }
    out[(size_t)row * 64 + c] = f2bf(invs[row] * acc);
}

__global__ __launch_bounds__(256) void k_gemm1(const float* __restrict__ h,
                                               const float* __restrict__ W,
                                               const float* __restrict__ invs,
                                               bfraw* __restrict__ out, int N) {
    __shared__ float sW[64 * 32];
    for (int i = threadIdx.x; i < 64 * 32; i += 256) sW[i] = W[i];
    __syncthreads();
    int row = blockIdx.x * 8 + (threadIdx.x >> 5);
    int c = threadIdx.x & 31;
    if (row >= N) return;
    const float4* hr = (const float4*)(h + (size_t)row * 64);
    float acc = 0.f;
#pragma unroll
    for (int k4 = 0; k4 < 16; ++k4) {
        float4 hv = hr[k4];
        int k = k4 * 4;
        acc = fmaf(hv.x, sW[(k + 0) * 32 + c], acc);
        acc = fmaf(hv.y, sW[(k + 1) * 32 + c], acc);
        acc = fmaf(hv.z, sW[(k + 2) * 32 + c], acc);
        acc = fmaf(hv.w, sW[(k + 3) * 32 + c], acc);
    }
    out[(size_t)row * 32 + c] = f2bf(invs[row] * acc);
}

// ---------------- CSR gather-aggregate (wide loads, multi-edge/wave) -------

// 16 lanes per edge-row (uint2 = 4 bf16/lane); 16 groups; 4 edges per wave req
__global__ __launch_bounds__(256) void k_csr_agg64(const int* __restrict__ scol,
                                                   const int* __restrict__ off,
                                                   const float* __restrict__ invs,
                                                   const bfraw* __restrict__ hWb,
                                                   const float* __restrict__ bias,
                                                   float* __restrict__ h0, int N) {
    int i = blockIdx.x;
    int tid = threadIdx.x;
    int l = tid & 15;          // features 4l..4l+3
    int g = tid >> 4;          // group 0..15
    int s = off[i], e = off[i + 1];
    float a0 = 0.f, a1 = 0.f, a2 = 0.f, a3 = 0.f;
    float c0a = 0.f, c1a = 0.f, c2a = 0.f, c3a = 0.f;
    int k = s + g;
    for (; k + 16 < e; k += 32) {
        int n0 = scol[k], n1 = scol[k + 16];
        uint2 u = *(const uint2*)(hWb + (size_t)n0 * 64 + l * 4);
        uint2 v = *(const uint2*)(hWb + (size_t)n1 * 64 + l * 4);
        a0 += bflo(u.x); a1 += bfhi(u.x); a2 += bflo(u.y); a3 += bfhi(u.y);
        c0a += bflo(v.x); c1a += bfhi(v.x); c2a += bflo(v.y); c3a += bfhi(v.y);
    }
    if (k < e) {
        int n0 = scol[k];
        uint2 u = *(const uint2*)(hWb + (size_t)n0 * 64 + l * 4);
        a0 += bflo(u.x); a1 += bfhi(u.x); a2 += bflo(u.y); a3 += bfhi(u.y);
    }
    a0 += c0a; a1 += c1a; a2 += c2a; a3 += c3a;
    __shared__ float red[16][64];
    red[g][l * 4 + 0] = a0;
    red[g][l * 4 + 1] = a1;
    red[g][l * 4 + 2] = a2;
    red[g][l * 4 + 3] = a3;
    __syncthreads();
    if (tid < 64) {
        float v = 0.f;
#pragma unroll
        for (int q = 0; q < 16; ++q) v += red[q][tid];
        v = invs[i] * (v + bf2f(hWb[(size_t)i * 64 + tid])) + bias[tid];
        h0[(size_t)i * 64 + tid] = v > 0.f ? v : 0.f;
    }
}

// 8 lanes per edge-row (uint2 = 4 bf16/lane); 32 groups; 8 edges per wave req
__global__ __launch_bounds__(256) void k_csr_agg32_pool(const int* __restrict__ scol,
                                                        const int* __restrict__ off,
                                                        const float* __restrict__ invs,
                                                        const bfraw* __restrict__ hWb,
                                                        const float* __restrict__ bias,
                                                        const int* __restrict__ gidx,
                                                        float* __restrict__ pooled,
                                                        int N) {
    int i = blockIdx.x;
    int tid = threadIdx.x;
    int l = tid & 7;           // features 4l..4l+3
    int g = tid >> 3;          // group 0..31
    int s = off[i], e = off[i + 1];
    float a0 = 0.f, a1 = 0.f, a2 = 0.f, a3 = 0.f;
    float c0a = 0.f, c1a = 0.f, c2a = 0.f, c3a = 0.f;
    int k = s + g;
    for (; k + 32 < e; k += 64) {
        int n0 = scol[k], n1 = scol[k + 32];
        uint2 u = *(const uint2*)(hWb + (size_t)n0 * 32 + l * 4);
        uint2 v = *(const uint2*)(hWb + (size_t)n1 * 32 + l * 4);
        a0 += bflo(u.x); a1 += bfhi(u.x); a2 += bflo(u.y); a3 += bfhi(u.y);
        c0a += bflo(v.x); c1a += bfhi(v.x); c2a += bflo(v.y); c3a += bfhi(v.y);
    }
    if (k < e) {
        int n0 = scol[k];
        uint2 u = *(const uint2*)(hWb + (size_t)n0 * 32 + l * 4);
        a0 += bflo(u.x); a1 += bfhi(u.x); a2 += bflo(u.y); a3 += bfhi(u.y);
    }
    a0 += c0a; a1 += c1a; a2 += c2a; a3 += c3a;
    __shared__ float red[32][32];
    red[g][l * 4 + 0] = a0;
    red[g][l * 4 + 1] = a1;
    red[g][l * 4 + 2] = a2;
    red[g][l * 4 + 3] = a3;
    __syncthreads();
    if (tid < 32) {
        float v = 0.f;
#pragma unroll
        for (int q = 0; q < 32; ++q) v += red[q][tid];
        v = invs[i] * (v + bf2f(hWb[(size_t)i * 32 + tid])) + bias[tid];
        v = v > 0.f ? v : 0.f;
        atomicAdd(&pooled[(size_t)gidx[i] * 32 + tid], v);
    }
}

__global__ __launch_bounds__(256) void k_cnt(const int* __restrict__ gidx,
                                             int* __restrict__ cnt, int N) {
    int i = blockIdx.x * 256 + threadIdx.x;
    if (i < N) atomicAdd(&cnt[gidx[i]], 1);
}

__global__ __launch_bounds__(256) void k_final(const float* __restrict__ pooled,
                                               const int* __restrict__ cnt,
                                               const float* __restrict__ Wd,
                                               const float* __restrict__ bd,
                                               float* __restrict__ out, int total) {
    int idx = blockIdx.x * 256 + threadIdx.x;
    if (idx >= total) return;
    int g = idx >> 4, c = idx & 15;
    float denom = fmaxf((float)cnt[g], 1.0f);
    float acc = 0.f;
#pragma unroll
    for (int j = 0; j < 32; ++j)
        acc = fmaf(pooled[g * 32 + j], Wd[j * 16 + c], acc);
    out[idx] = acc / denom + bd[c];
}

// ---------------- launch ----------------

static inline size_t align256(size_t v) { return (v + 255) & ~(size_t)255; }

extern "C" void kernel_launch(void* const* d_in, const int* in_sizes, int n_in,
                              void* d_out, int out_size, void* d_ws, size_t ws_size,
                              hipStream_t stream) {
    const float* x   = (const float*)d_in[0];
    const int*  erow = (const int*)d_in[1];              // edge targets
    const int*  gidx = (const int*)d_in[2];
    const float* W0  = (const float*)d_in[3];
    const float* b0  = (const float*)d_in[4];
    const float* W1  = (const float*)d_in[5];
    const float* b1  = (const float*)d_in[6];
    const float* Wd  = (const float*)d_in[7];
    const float* bd  = (const float*)d_in[8];
    float* out = (float*)d_out;

    const int E = in_sizes[1] / 2;
    const int* ecol = erow + E;                          // edge sources
    const int N = in_sizes[2];
    const int G = out_size / 16;
    const int nbuckets = (N + BSIZE - 1) / BSIZE;
    const int nchunks = (E + CHUNK - 1) / CHUNK;

    char* ws = (char*)d_ws;
    size_t oInvs = 0;                                                 // N f32
    size_t oOff  = align256(oInvs + (size_t)N * 4);                   // (N+8) ints
    size_t oBh   = align256(oOff + (size_t)(N + 8) * 4);              // MAXB ints
    size_t oBo   = align256(oBh + (size_t)MAXB * 4);                  // MAXB+8 ints
    size_t oBc   = align256(oBo + (size_t)(MAXB + 8) * 4);            // MAXB ints
    size_t oScol = align256(oBc + (size_t)MAXB * 4);                  // E ints
    size_t oA    = align256(oScol + (size_t)E * 4);                   // N*64 bf16
    size_t oB    = align256(oA + (size_t)N * 128);                    // bedge / h0
    size_t oP    = align256(oB + (size_t)N * 256);                    // G*32 f32
    size_t oCnt  = align256(oP + (size_t)G * 128);                    // G ints

    float* invs   = (float*)(ws + oInvs);
    int*   off    = (int*)(ws + oOff);
    int*   bhist  = (int*)(ws + oBh);
    int*   boff   = (int*)(ws + oBo);
    int*   bcur   = (int*)(ws + oBc);
    int*   scol   = (int*)(ws + oScol);
    bfraw* tabA   = (bfraw*)(ws + oA);
    float* bufB   = (float*)(ws + oB);
    float* pooled = (float*)(ws + oP);
    int*   cnt    = (int*)(ws + oCnt);
    int*   bedge  = (int*)bufB;                          // dead before h0 is written

    hipMemsetAsync(bhist, 0, (size_t)MAXB * 4, stream);
    hipMemsetAsync(pooled, 0, (size_t)G * 128 + (size_t)G * 4, stream);

    // CSR build via two-level counting sort (also yields deg -> invs)
    k_bhist<<<nchunks, 256, 0, stream>>>(erow, bhist, E, nbuckets);
    k_bscan<<<1, 1024, 0, stream>>>(bhist, boff, bcur, nbuckets, E);
    k_bscatter<<<nchunks, 256, 0, stream>>>(erow, ecol, bcur, bedge, E, nbuckets);
    k_bexact<<<nbuckets, 256, 0, stream>>>(bedge, boff, off, scol, invs, N, E);

    // layer 0: project (invs-scaled, bf16) then gather-aggregate
    k_gemm0<<<(N + 3) / 4, 256, 0, stream>>>(x, W0, invs, tabA, N);
    k_csr_agg64<<<N, 256, 0, stream>>>(scol, off, invs, tabA, b0, bufB, N);

    // layer 1: project then gather-aggregate fused with mean-pool
    k_gemm1<<<(N + 7) / 8, 256, 0, stream>>>(bufB, W1, invs, tabA, N);
    k_csr_agg32_pool<<<N, 256, 0, stream>>>(scol, off, invs, tabA, b1, gidx, pooled, N);
    k_cnt<<<(N + 255) / 256, 256, 0, stream>>>(gidx, cnt, N);

    // dense head
    k_final<<<(G * 16 + 255) / 256, 256, 0, stream>>>(pooled, cnt, Wd, bd, out, G * 16);
}

// Round 6
// 488.807 us; speedup vs baseline: 1.5639x; 1.2142x over previous
//
#include <hip/hip_runtime.h>

#define BSHIFT 7
#define BSIZE 128          // nodes per bucket
#define MAXB 1024          // max buckets (N <= 131072); col must fit 17 bits
#define CHUNK 16384        // edges per block in bucket passes

typedef unsigned short bfraw;

__device__ __forceinline__ bfraw f2bf(float f) {
    unsigned u = __float_as_uint(f);
    unsigned r = u + 0x7FFFu + ((u >> 16) & 1u);   // round-to-nearest-even
    return (bfraw)(r >> 16);
}
__device__ __forceinline__ float bf2f(bfraw h) {
    return __uint_as_float(((unsigned)h) << 16);
}
__device__ __forceinline__ float bflo(unsigned u) { return __uint_as_float(u << 16); }
__device__ __forceinline__ float bfhi(unsigned u) { return __uint_as_float(u & 0xFFFF0000u); }

// ---------------- bucketed CSR build ----------------

__global__ __launch_bounds__(256) void k_bhist(const int* __restrict__ row,
                                               int* __restrict__ bhist,
                                               int E, int nbuckets) {
    __shared__ int h[MAXB];
    for (int i = threadIdx.x; i < nbuckets; i += 256) h[i] = 0;
    __syncthreads();
    int start = blockIdx.x * CHUNK;
    int end = min(E, start + CHUNK);
    for (int i = start + threadIdx.x; i < end; i += 256)
        atomicAdd(&h[row[i] >> BSHIFT], 1);
    __syncthreads();
    for (int i = threadIdx.x; i < nbuckets; i += 256)
        if (h[i]) atomicAdd(&bhist[i], h[i]);
}

__global__ __launch_bounds__(1024) void k_bscan(const int* __restrict__ bhist,
                                                int* __restrict__ boff,
                                                int* __restrict__ bcur,
                                                int nbuckets, int E) {
    __shared__ int sd[1024];
    int t = threadIdx.x;
    int v = (t < nbuckets) ? bhist[t] : 0;
    sd[t] = v;
    __syncthreads();
    for (int d = 1; d < 1024; d <<= 1) {
        int a = (t >= d) ? sd[t - d] : 0;
        __syncthreads();
        sd[t] += a;
        __syncthreads();
    }
    if (t < nbuckets) { int ex = sd[t] - v; boff[t] = ex; bcur[t] = ex; }
    if (t == 0) boff[nbuckets] = E;
}

__global__ __launch_bounds__(256) void k_bscatter(const int* __restrict__ row,
                                                  const int* __restrict__ col,
                                                  int* __restrict__ bcur,
                                                  int* __restrict__ bedge,
                                                  int E, int nbuckets) {
    __shared__ int h[MAXB];
    __shared__ int base[MAXB];
    for (int i = threadIdx.x; i < nbuckets; i += 256) h[i] = 0;
    __syncthreads();
    int start = blockIdx.x * CHUNK;
    int end = min(E, start + CHUNK);
    for (int i = start + threadIdx.x; i < end; i += 256)
        atomicAdd(&h[row[i] >> BSHIFT], 1);
    __syncthreads();
    for (int i = threadIdx.x; i < nbuckets; i += 256) {
        int c = h[i];
        base[i] = c ? atomicAdd(&bcur[i], c) : 0;
        h[i] = 0;
    }
    __syncthreads();
    for (int i = start + threadIdx.x; i < end; i += 256) {
        int r = row[i], c = col[i];
        int b = r >> BSHIFT;
        int p = base[b] + atomicAdd(&h[b], 1);
        bedge[p] = ((r & (BSIZE - 1)) << 17) | c;
    }
}

__global__ __launch_bounds__(256) void k_bexact(const int* __restrict__ bedge,
                                                const int* __restrict__ boff,
                                                int* __restrict__ off,
                                                int* __restrict__ scol,
                                                float* __restrict__ invs,
                                                int N, int E) {
    __shared__ int ldeg[BSIZE];
    __shared__ int lex[BSIZE];
    int b = blockIdx.x;
    int tid = threadIdx.x;
    int nstart = b << BSHIFT;
    int ncount = min(BSIZE, N - nstart);
    int s = boff[b], e = boff[b + 1];
    if (tid < BSIZE) ldeg[tid] = 0;
    __syncthreads();
    for (int k = s + tid; k < e; k += 256)
        atomicAdd(&ldeg[bedge[k] >> 17], 1);
    __syncthreads();
    if (tid < BSIZE) lex[tid] = ldeg[tid];
    __syncthreads();
    for (int d = 1; d < BSIZE; d <<= 1) {
        int a = 0;
        if (tid < BSIZE && tid >= d) a = lex[tid - d];
        __syncthreads();
        if (tid < BSIZE) lex[tid] += a;
        __syncthreads();
    }
    if (tid < BSIZE) lex[tid] -= ldeg[tid];   // exclusive scan
    __syncthreads();
    if (tid < ncount) {
        int node = nstart + tid;
        off[node] = s + lex[tid];
        invs[node] = rsqrtf((float)(ldeg[tid] + 1));
    }
    if (b == 0 && tid == 0) off[N] = E;
    if (tid < BSIZE) ldeg[tid] = 0;           // reuse as per-node cursor
    __syncthreads();
    for (int k = s + tid; k < e; k += 256) {
        int p = bedge[k];
        int lr = p >> 17;
        int pos = s + lex[lr] + atomicAdd(&ldeg[lr], 1);
        scol[pos] = p & 0x1FFFF;
    }
}

// ------------- projections: 4x4 register tile, W in LDS, x via L1 ----------

// x[N,128] @ W0[128,64] -> bf16 out scaled by invs[row]; 64 rows x 64 cols/block
__global__ __launch_bounds__(256) void k_gemm0(const float* __restrict__ x,
                                               const float* __restrict__ W,
                                               const float* __restrict__ invs,
                                               bfraw* __restrict__ out, int N) {
    __shared__ float sW[128 * 64];
    for (int i = threadIdx.x; i < 2048; i += 256)
        ((float4*)sW)[i] = ((const float4*)W)[i];
    __syncthreads();
    int t = threadIdx.x;
    int tc = t & 15, tr = t >> 4;            // cols 4tc.., rows 4tr..
    int r0 = blockIdx.x * 64;
    int rbase = r0 + tr * 4;
    float acc[4][4] = {};
    // clamp rows for safe OOB loads (results discarded on store)
    int rr[4];
#pragma unroll
    for (int i = 0; i < 4; ++i) rr[i] = min(rbase + i, N - 1);
    for (int k = 0; k < 128; k += 4) {
        float4 wv0 = *(const float4*)&sW[(k + 0) * 64 + tc * 4];
        float4 wv1 = *(const float4*)&sW[(k + 1) * 64 + tc * 4];
        float4 wv2 = *(const float4*)&sW[(k + 2) * 64 + tc * 4];
        float4 wv3 = *(const float4*)&sW[(k + 3) * 64 + tc * 4];
#pragma unroll
        for (int i = 0; i < 4; ++i) {
            float4 xv = *(const float4*)(x + (size_t)rr[i] * 128 + k);
            acc[i][0] = fmaf(xv.x, wv0.x, acc[i][0]);
            acc[i][1] = fmaf(xv.x, wv0.y, acc[i][1]);
            acc[i][2] = fmaf(xv.x, wv0.z, acc[i][2]);
            acc[i][3] = fmaf(xv.x, wv0.w, acc[i][3]);
            acc[i][0] = fmaf(xv.y, wv1.x, acc[i][0]);
            acc[i][1] = fmaf(xv.y, wv1.y, acc[i][1]);
            acc[i][2] = fmaf(xv.y, wv1.z, acc[i][2]);
            acc[i][3] = fmaf(xv.y, wv1.w, acc[i][3]);
            acc[i][0] = fmaf(xv.z, wv2.x, acc[i][0]);
            acc[i][1] = fmaf(xv.z, wv2.y, acc[i][1]);
            acc[i][2] = fmaf(xv.z, wv2.z, acc[i][2]);
            acc[i][3] = fmaf(xv.z, wv2.w, acc[i][3]);
            acc[i][0] = fmaf(xv.w, wv3.x, acc[i][0]);
            acc[i][1] = fmaf(xv.w, wv3.y, acc[i][1]);
            acc[i][2] = fmaf(xv.w, wv3.z, acc[i][2]);
            acc[i][3] = fmaf(xv.w, wv3.w, acc[i][3]);
        }
    }
#pragma unroll
    for (int i = 0; i < 4; ++i) {
        int row = rbase + i;
        if (row < N) {
            float iv = invs[row];
            ushort4 o;
            o.x = f2bf(iv * acc[i][0]);
            o.y = f2bf(iv * acc[i][1]);
            o.z = f2bf(iv * acc[i][2]);
            o.w = f2bf(iv * acc[i][3]);
            *(ushort4*)(out + (size_t)row * 64 + tc * 4) = o;
        }
    }
}

// h0[N,64] @ W1[64,32] -> bf16 out scaled; 128 rows x 32 cols per block
__global__ __launch_bounds__(256) void k_gemm1(const float* __restrict__ h,
                                               const float* __restrict__ W,
                                               const float* __restrict__ invs,
                                               bfraw* __restrict__ out, int N) {
    __shared__ float sW[64 * 32];
    for (int i = threadIdx.x; i < 512; i += 256)
        ((float4*)sW)[i] = ((const float4*)W)[i];
    __syncthreads();
    int t = threadIdx.x;
    int tc = t & 7, tr = t >> 3;             // cols 4tc.., rows 4tr..
    int r0 = blockIdx.x * 128;
    int rbase = r0 + tr * 4;
    float acc[4][4] = {};
    int rr[4];
#pragma unroll
    for (int i = 0; i < 4; ++i) rr[i] = min(rbase + i, N - 1);
    for (int k = 0; k < 64; k += 4) {
        float4 wv0 = *(const float4*)&sW[(k + 0) * 32 + tc * 4];
        float4 wv1 = *(const float4*)&sW[(k + 1) * 32 + tc * 4];
        float4 wv2 = *(const float4*)&sW[(k + 2) * 32 + tc * 4];
        float4 wv3 = *(const float4*)&sW[(k + 3) * 32 + tc * 4];
#pragma unroll
        for (int i = 0; i < 4; ++i) {
            float4 xv = *(const float4*)(h + (size_t)rr[i] * 64 + k);
            acc[i][0] = fmaf(xv.x, wv0.x, acc[i][0]);
            acc[i][1] = fmaf(xv.x, wv0.y, acc[i][1]);
            acc[i][2] = fmaf(xv.x, wv0.z, acc[i][2]);
            acc[i][3] = fmaf(xv.x, wv0.w, acc[i][3]);
            acc[i][0] = fmaf(xv.y, wv1.x, acc[i][0]);
            acc[i][1] = fmaf(xv.y, wv1.y, acc[i][1]);
            acc[i][2] = fmaf(xv.y, wv1.z, acc[i][2]);
            acc[i][3] = fmaf(xv.y, wv1.w, acc[i][3]);
            acc[i][0] = fmaf(xv.z, wv2.x, acc[i][0]);
            acc[i][1] = fmaf(xv.z, wv2.y, acc[i][1]);
            acc[i][2] = fmaf(xv.z, wv2.z, acc[i][2]);
            acc[i][3] = fmaf(xv.z, wv2.w, acc[i][3]);
            acc[i][0] = fmaf(xv.w, wv3.x, acc[i][0]);
            acc[i][1] = fmaf(xv.w, wv3.y, acc[i][1]);
            acc[i][2] = fmaf(xv.w, wv3.z, acc[i][2]);
            acc[i][3] = fmaf(xv.w, wv3.w, acc[i][3]);
        }
    }
#pragma unroll
    for (int i = 0; i < 4; ++i) {
        int row = rbase + i;
        if (row < N) {
            float iv = invs[row];
            ushort4 o;
            o.x = f2bf(iv * acc[i][0]);
            o.y = f2bf(iv * acc[i][1]);
            o.z = f2bf(iv * acc[i][2]);
            o.w = f2bf(iv * acc[i][3]);
            *(ushort4*)(out + (size_t)row * 32 + tc * 4) = o;
        }
    }
}

// ---------------- CSR gather-aggregate (wide loads, multi-edge/wave) -------

__global__ __launch_bounds__(256) void k_csr_agg64(const int* __restrict__ scol,
                                                   const int* __restrict__ off,
                                                   const float* __restrict__ invs,
                                                   const bfraw* __restrict__ hWb,
                                                   const float* __restrict__ bias,
                                                   float* __restrict__ h0, int N) {
    int i = blockIdx.x;
    int tid = threadIdx.x;
    int l = tid & 15;          // features 4l..4l+3
    int g = tid >> 4;          // group 0..15
    int s = off[i], e = off[i + 1];
    float a0 = 0.f, a1 = 0.f, a2 = 0.f, a3 = 0.f;
    float c0a = 0.f, c1a = 0.f, c2a = 0.f, c3a = 0.f;
    int k = s + g;
    for (; k + 16 < e; k += 32) {
        int n0 = scol[k], n1 = scol[k + 16];
        uint2 u = *(const uint2*)(hWb + (size_t)n0 * 64 + l * 4);
        uint2 v = *(const uint2*)(hWb + (size_t)n1 * 64 + l * 4);
        a0 += bflo(u.x); a1 += bfhi(u.x); a2 += bflo(u.y); a3 += bfhi(u.y);
        c0a += bflo(v.x); c1a += bfhi(v.x); c2a += bflo(v.y); c3a += bfhi(v.y);
    }
    if (k < e) {
        int n0 = scol[k];
        uint2 u = *(const uint2*)(hWb + (size_t)n0 * 64 + l * 4);
        a0 += bflo(u.x); a1 += bfhi(u.x); a2 += bflo(u.y); a3 += bfhi(u.y);
    }
    a0 += c0a; a1 += c1a; a2 += c2a; a3 += c3a;
    __shared__ float red[16][64];
    red[g][l * 4 + 0] = a0;
    red[g][l * 4 + 1] = a1;
    red[g][l * 4 + 2] = a2;
    red[g][l * 4 + 3] = a3;
    __syncthreads();
    if (tid < 64) {
        float v = 0.f;
#pragma unroll
        for (int q = 0; q < 16; ++q) v += red[q][tid];
        v = invs[i] * (v + bf2f(hWb[(size_t)i * 64 + tid])) + bias[tid];
        h0[(size_t)i * 64 + tid] = v > 0.f ? v : 0.f;
    }
}

__global__ __launch_bounds__(256) void k_csr_agg32_pool(const int* __restrict__ scol,
                                                        const int* __restrict__ off,
                                                        const float* __restrict__ invs,
                                                        const bfraw* __restrict__ hWb,
                                                        const float* __restrict__ bias,
                                                        const int* __restrict__ gidx,
                                                        float* __restrict__ pooled,
                                                        int N) {
    int i = blockIdx.x;
    int tid = threadIdx.x;
    int l = tid & 7;           // features 4l..4l+3
    int g = tid >> 3;          // group 0..31
    int s = off[i], e = off[i + 1];
    float a0 = 0.f, a1 = 0.f, a2 = 0.f, a3 = 0.f;
    float c0a = 0.f, c1a = 0.f, c2a = 0.f, c3a = 0.f;
    int k = s + g;
    for (; k + 32 < e; k += 64) {
        int n0 = scol[k], n1 = scol[k + 32];
        uint2 u = *(const uint2*)(hWb + (size_t)n0 * 32 + l * 4);
        uint2 v = *(const uint2*)(hWb + (size_t)n1 * 32 + l * 4);
        a0 += bflo(u.x); a1 += bfhi(u.x); a2 += bflo(u.y); a3 += bfhi(u.y);
        c0a += bflo(v.x); c1a += bfhi(v.x); c2a += bflo(v.y); c3a += bfhi(v.y);
    }
    if (k < e) {
        int n0 = scol[k];
        uint2 u = *(const uint2*)(hWb + (size_t)n0 * 32 + l * 4);
        a0 += bflo(u.x); a1 += bfhi(u.x); a2 += bflo(u.y); a3 += bfhi(u.y);
    }
    a0 += c0a; a1 += c1a; a2 += c2a; a3 += c3a;
    __shared__ float red[32][32];
    red[g][l * 4 + 0] = a0;
    red[g][l * 4 + 1] = a1;
    red[g][l * 4 + 2] = a2;
    red[g][l * 4 + 3] = a3;
    __syncthreads();
    if (tid < 32) {
        float v = 0.f;
#pragma unroll
        for (int q = 0; q < 32; ++q) v += red[q][tid];
        v = invs[i] * (v + bf2f(hWb[(size_t)i * 32 + tid])) + bias[tid];
        v = v > 0.f ? v : 0.f;
        atomicAdd(&pooled[(size_t)gidx[i] * 32 + tid], v);
    }
}

__global__ __launch_bounds__(256) void k_cnt(const int* __restrict__ gidx,
                                             int* __restrict__ cnt, int N) {
    int i = blockIdx.x * 256 + threadIdx.x;
    if (i < N) atomicAdd(&cnt[gidx[i]], 1);
}

__global__ __launch_bounds__(256) void k_final(const float* __restrict__ pooled,
                                               const int* __restrict__ cnt,
                                               const float* __restrict__ Wd,
                                               const float* __restrict__ bd,
                                               float* __restrict__ out, int total) {
    int idx = blockIdx.x * 256 + threadIdx.x;
    if (idx >= total) return;
    int g = idx >> 4, c = idx & 15;
    float denom = fmaxf((float)cnt[g], 1.0f);
    float acc = 0.f;
#pragma unroll
    for (int j = 0; j < 32; ++j)
        acc = fmaf(pooled[g * 32 + j], Wd[j * 16 + c], acc);
    out[idx] = acc / denom + bd[c];
}

// ---------------- launch ----------------

static inline size_t align256(size_t v) { return (v + 255) & ~(size_t)255; }

extern "C" void kernel_launch(void* const* d_in, const int* in_sizes, int n_in,
                              void* d_out, int out_size, void* d_ws, size_t ws_size,
                              hipStream_t stream) {
    const float* x   = (const float*)d_in[0];
    const int*  erow = (const int*)d_in[1];              // edge targets
    const int*  gidx = (const int*)d_in[2];
    const float* W0  = (const float*)d_in[3];
    const float* b0  = (const float*)d_in[4];
    const float* W1  = (const float*)d_in[5];
    const float* b1  = (const float*)d_in[6];
    const float* Wd  = (const float*)d_in[7];
    const float* bd  = (const float*)d_in[8];
    float* out = (float*)d_out;

    const int E = in_sizes[1] / 2;
    const int* ecol = erow + E;                          // edge sources
    const int N = in_sizes[2];
    const int G = out_size / 16;
    const int nbuckets = (N + BSIZE - 1) / BSIZE;
    const int nchunks = (E + CHUNK - 1) / CHUNK;

    char* ws = (char*)d_ws;
    size_t oInvs = 0;                                                 // N f32
    size_t oOff  = align256(oInvs + (size_t)N * 4);                   // (N+8) ints
    size_t oBh   = align256(oOff + (size_t)(N + 8) * 4);              // MAXB ints
    size_t oBo   = align256(oBh + (size_t)MAXB * 4);                  // MAXB+8 ints
    size_t oBc   = align256(oBo + (size_t)(MAXB + 8) * 4);            // MAXB ints
    size_t oScol = align256(oBc + (size_t)MAXB * 4);                  // E ints
    size_t oA    = align256(oScol + (size_t)E * 4);                   // N*64 bf16
    size_t oB    = align256(oA + (size_t)N * 128);                    // bedge / h0
    size_t oP    = align256(oB + (size_t)N * 256);                    // G*32 f32
    size_t oCnt  = align256(oP + (size_t)G * 128);                    // G ints

    float* invs   = (float*)(ws + oInvs);
    int*   off    = (int*)(ws + oOff);
    int*   bhist  = (int*)(ws + oBh);
    int*   boff   = (int*)(ws + oBo);
    int*   bcur   = (int*)(ws + oBc);
    int*   scol   = (int*)(ws + oScol);
    bfraw* tabA   = (bfraw*)(ws + oA);
    float* bufB   = (float*)(ws + oB);
    float* pooled = (float*)(ws + oP);
    int*   cnt    = (int*)(ws + oCnt);
    int*   bedge  = (int*)bufB;                          // dead before h0 is written

    hipMemsetAsync(bhist, 0, (size_t)MAXB * 4, stream);
    hipMemsetAsync(pooled, 0, (size_t)G * 128 + (size_t)G * 4, stream);

    // CSR build via two-level counting sort (also yields deg -> invs)
    k_bhist<<<nchunks, 256, 0, stream>>>(erow, bhist, E, nbuckets);
    k_bscan<<<1, 1024, 0, stream>>>(bhist, boff, bcur, nbuckets, E);
    k_bscatter<<<nchunks, 256, 0, stream>>>(erow, ecol, bcur, bedge, E, nbuckets);
    k_bexact<<<nbuckets, 256, 0, stream>>>(bedge, boff, off, scol, invs, N, E);

    // layer 0: project (invs-scaled, bf16) then gather-aggregate
    k_gemm0<<<(N + 63) / 64, 256, 0, stream>>>(x, W0, invs, tabA, N);
    k_csr_agg64<<<N, 256, 0, stream>>>(scol, off, invs, tabA, b0, bufB, N);

    // layer 1: project then gather-aggregate fused with mean-pool
    k_gemm1<<<(N + 127) / 128, 256, 0, stream>>>(bufB, W1, invs, tabA, N);
    k_csr_agg32_pool<<<N, 256, 0, stream>>>(scol, off, invs, tabA, b1, gidx, pooled, N);
    k_cnt<<<(N + 255) / 256, 256, 0, stream>>>(gidx, cnt, N);

    // dense head
    k_final<<<(G * 16 + 255) / 256, 256, 0, stream>>>(pooled, cnt, Wd, bd, out, G * 16);
}